// Round 12
// baseline (287.109 us; speedup 1.0000x reference)
//
#include <hip/hip_runtime.h>
#include <hip/hip_bf16.h>
#include <cstdint>

// ---- problem constants ----
#define S_LEN  1024
#define DMODEL 1024
#define NTOK   4096   // B*S = 4*1024
#define NHEAD  16
#define HDIM   64
#define FFDIM  4096
#define NBATCH 4
#define QSCALE 0.1803368801f   // 0.125 * log2(e): folds attn scale + exp->exp2 into Q

using bf16x8 = __attribute__((ext_vector_type(8))) short;
using f32x4  = __attribute__((ext_vector_type(4))) float;

__device__ __forceinline__ ushort f2bf(float f) {
  union { float f; uint32_t u; } a; a.f = f;
  uint32_t u = a.u;
  u += 0x7FFFu + ((u >> 16) & 1u);   // RNE
  return (ushort)(u >> 16);
}
// HW pack-convert, 1 VALU op (RNE on gfx950)
__device__ __forceinline__ ushort f2bf_hw(float f) {
  uint32_t r;
  asm("v_cvt_pk_bf16_f32 %0, %1, %1" : "=v"(r) : "v"(f));
  return (ushort)r;
}
__device__ __forceinline__ float bf2f(ushort u) {
  union { uint32_t u; float f; } c; c.u = ((uint32_t)u) << 16; return c.f;
}
__device__ __forceinline__ float ld_as_float(const float* p, long i) { return p[i]; }
__device__ __forceinline__ float ld_as_float(const ushort* p, long i) { return bf2f(p[i]); }
__device__ __forceinline__ void st_out(float* C, long i, float v) { C[i] = v; }
__device__ __forceinline__ void st_out(ushort* C, long i, float v) { C[i] = f2bf(v); }

// async global->LDS, 16B per lane; LDS dest = wave-uniform base + lane*16 (linear!)
__device__ __forceinline__ void gld_lds16(const void* g, void* l) {
  __builtin_amdgcn_global_load_lds((const __attribute__((address_space(1))) void*)g,
                                   (__attribute__((address_space(3))) void*)l, 16, 0, 0);
}

// ---------------- LayerNorm (row of 1024 f32) -> bf16 ----------------
__global__ __launch_bounds__(256) void ln_kernel(const float* __restrict__ x,
    const float* __restrict__ g, const float* __restrict__ b,
    ushort* __restrict__ out) {
  int row = blockIdx.x;
  int tid = threadIdx.x;
  const float4* xr = (const float4*)(x + (long)row * DMODEL);
  float4 v = xr[tid];
  float s  = v.x + v.y + v.z + v.w;
  float s2 = v.x*v.x + v.y*v.y + v.z*v.z + v.w*v.w;
  for (int off = 32; off; off >>= 1) { s += __shfl_down(s, off); s2 += __shfl_down(s2, off); }
  __shared__ float red[8];
  int wid = tid >> 6, lane = tid & 63;
  if (lane == 0) { red[wid] = s; red[wid + 4] = s2; }
  __syncthreads();
  if (tid == 0) {
    red[0] = red[0] + red[1] + red[2] + red[3];
    red[4] = red[4] + red[5] + red[6] + red[7];
  }
  __syncthreads();
  float mu  = red[0] * (1.0f / DMODEL);
  float var = red[4] * (1.0f / DMODEL) - mu * mu;
  float rs  = rsqrtf(var + 1e-5f);
  float4 gg = ((const float4*)g)[tid];
  float4 bb = ((const float4*)b)[tid];
  ushort4 o;
  o.x = f2bf((v.x - mu) * rs * gg.x + bb.x);
  o.y = f2bf((v.y - mu) * rs * gg.y + bb.y);
  o.z = f2bf((v.z - mu) * rs * gg.z + bb.z);
  o.w = f2bf((v.w - mu) * rs * gg.w + bb.w);
  ((ushort4*)(out + (long)row * DMODEL))[tid] = o;
}

// ---------------- bias concat: [bq|bk|bv] -> 3072 floats ----------------
__global__ __launch_bounds__(256) void concat3(const float* __restrict__ a,
    const float* __restrict__ b, const float* __restrict__ c, float* __restrict__ o) {
  int i = blockIdx.x * 256 + threadIdx.x;
  o[i] = (i < 1024) ? a[i] : ((i < 2048) ? b[i - 1024] : c[i - 2048]);
}

// ---------------- partial reduce: out = out + bias + sum(parts) ----------------
template <int NP>
__global__ __launch_bounds__(256) void reduce_add(
    const ushort* __restrict__ parts, const float* __restrict__ bias,
    float* __restrict__ out) {
  long i = (long)blockIdx.x * 256 + threadIdx.x;   // float4 index
  const long PSTRIDE = (long)NTOK * DMODEL / 4;    // in ushort4 units
  float4 acc = ((const float4*)out)[i];
  float4 b = ((const float4*)bias)[i & 255];
  acc.x += b.x; acc.y += b.y; acc.z += b.z; acc.w += b.w;
#pragma unroll
  for (int z = 0; z < NP; ++z) {
    ushort4 u = ((const ushort4*)parts)[z * PSTRIDE + i];
    acc.x += bf2f(u.x); acc.y += bf2f(u.y); acc.z += bf2f(u.z); acc.w += bf2f(u.w);
  }
  ((float4*)out)[i] = acc;
}

// ---- fused: out = x + bias + sum(parts); hout = LN(out)*g+b (bf16). 1 block/row. ----
template <int NP>
__global__ __launch_bounds__(256) void reduce_ln(
    const ushort* __restrict__ parts, const float* __restrict__ xres,
    const float* __restrict__ bias, float* __restrict__ out,
    const float* __restrict__ g, const float* __restrict__ bln,
    ushort* __restrict__ hout) {
  int row = blockIdx.x, tid = threadIdx.x;
  long i = (long)row * 256 + tid;
  const long PSTRIDE = (long)NTOK * DMODEL / 4;
  float4 v = ((const float4*)xres)[i];
  float4 b = ((const float4*)bias)[tid];
  v.x += b.x; v.y += b.y; v.z += b.z; v.w += b.w;
#pragma unroll
  for (int z = 0; z < NP; ++z) {
    ushort4 u = ((const ushort4*)parts)[z * PSTRIDE + i];
    v.x += bf2f(u.x); v.y += bf2f(u.y); v.z += bf2f(u.z); v.w += bf2f(u.w);
  }
  ((float4*)out)[i] = v;
  // LN over the row
  float s  = v.x + v.y + v.z + v.w;
  float s2 = v.x*v.x + v.y*v.y + v.z*v.z + v.w*v.w;
  for (int off = 32; off; off >>= 1) { s += __shfl_down(s, off); s2 += __shfl_down(s2, off); }
  __shared__ float red[8];
  int wid = tid >> 6, lane = tid & 63;
  if (lane == 0) { red[wid] = s; red[wid + 4] = s2; }
  __syncthreads();
  if (tid == 0) {
    red[0] = red[0] + red[1] + red[2] + red[3];
    red[4] = red[4] + red[5] + red[6] + red[7];
  }
  __syncthreads();
  float mu  = red[0] * (1.0f / DMODEL);
  float var = red[4] * (1.0f / DMODEL) - mu * mu;
  float rs  = rsqrtf(var + 1e-5f);
  float4 gg = ((const float4*)g)[tid];
  float4 bb = ((const float4*)bln)[tid];
  ushort4 o;
  o.x = f2bf((v.x - mu) * rs * gg.x + bb.x);
  o.y = f2bf((v.y - mu) * rs * gg.y + bb.y);
  o.z = f2bf((v.z - mu) * rs * gg.z + bb.z);
  o.w = f2bf((v.w - mu) * rs * gg.w + bb.w);
  ((ushort4*)hout)[i] = o;
}

// ---------------- transpose + convert to bf16 ----------------
template <typename TIN>
__global__ __launch_bounds__(256) void transpose_cvt(const TIN* __restrict__ in,
    ushort* __restrict__ out, int ldin, int ldout,
    long inZhi, long inZlo, long outZ) {
  int z = blockIdx.z;
  in  += (long)(z >> 4) * inZhi + (long)(z & 15) * inZlo;
  out += (long)z * outZ;
  __shared__ float tile[32][33];
  int c0 = blockIdx.x * 32, r0 = blockIdx.y * 32;
  int tx = threadIdx.x, ty = threadIdx.y;
  for (int i = ty; i < 32; i += 8)
    tile[i][tx] = ld_as_float(in, (long)(r0 + i) * ldin + c0 + tx);
  __syncthreads();
  for (int i = ty; i < 32; i += 8)
    out[(long)(c0 + i) * ldout + r0 + tx] = f2bf(tile[tx][i]);
}

// ---------------- 128x128 bf16 MFMA GEMM — m97 structure ----------------
// Single-buffered 32KB LDS, plain __syncthreads (compiler drains), 4 waves (2x2),
// 16x16x32 MFMA, global_load_lds width-16, T2 staging involution (slot s of row r
// holds k-grp s^(r&7); read XORs the same), XCD-chunked block swizzle.
// Occupancy: ~32KB LDS + ~150 regs -> 3-4 blocks/CU; inter-block overlap (m114)
// hides the per-tile vmcnt drain. This is the measured 874-912 TF operating point.
// split-K: blockIdx.z = chunk; A/B advance z*aZlo/z*bZlo (elements), C by z*cZlo.
// ACT: 0=none, 1=exact gelu, 2=scale cols<DMODEL by QSCALE (Q pre-scale).
template <int ACT, bool BIAS, typename TOUT>
__global__ __launch_bounds__(256) void gemm_bt(
    const ushort* __restrict__ A, const ushort* __restrict__ BT, TOUT* __restrict__ C,
    const float* __restrict__ bias,
    int M, int K, int lda, int ldb, int ldc,
    long aZlo, long bZlo, long cZlo) {
  __shared__ __align__(16) ushort lA[128 * 64];
  __shared__ __align__(16) ushort lB[128 * 64];
  int z = blockIdx.z;
  A  += (long)z * aZlo;
  BT += (long)z * bZlo;
  C  += (long)z * cZlo;
  // XCD-chunked bijective swizzle (requires gridDim.x*gridDim.y % 8 == 0)
  int gx = gridDim.x;
  int nwg = gx * gridDim.y;
  int lin = blockIdx.x + gx * blockIdx.y;
  int wg = (lin & 7) * (nwg >> 3) + (lin >> 3);
  int n0 = (wg / gx) * 128, m0 = (wg % gx) * 128;
  int tid = threadIdx.x, lane = tid & 63, wid = tid >> 6;
  int wr = wid >> 1, wc = wid & 1;
  int lrow = lane >> 3;                       // 0..7
  int swz = ((lane & 7) ^ lrow) << 3;         // pre-swizzled global k-offset (elements)
  f32x4 acc[4][4];
#pragma unroll
  for (int i = 0; i < 4; i++)
#pragma unroll
    for (int j = 0; j < 4; j++) acc[i][j] = (f32x4){0.f, 0.f, 0.f, 0.f};

  int nK = K >> 6;
  for (int kt = 0; kt < nK; ++kt) {
    const ushort* Ak = A + (kt << 6) + swz;
    const ushort* Bk = BT + (kt << 6) + swz;
#pragma unroll
    for (int c = 0; c < 4; ++c) {
      int ch = (wid << 2) | c;          // chunk 0..15 (8 rows each)
      int rb = (ch << 3) + lrow;        // row 0..127
      gld_lds16(Ak + (long)(n0 + rb) * lda, &lA[ch << 9]);
      gld_lds16(Bk + (long)(m0 + rb) * ldb, &lB[ch << 9]);
    }
    __syncthreads();                    // drains vmcnt; data visible
#pragma unroll
    for (int kk = 0; kk < 2; ++kk) {
      int g = (kk << 2) | (lane >> 4);
      int kfs = ((g ^ (lane & 7)) << 3);
      bf16x8 af[4], bfr[4];
#pragma unroll
      for (int i = 0; i < 4; i++) {
        af[i]  = *(const bf16x8*)(&lA[((wr << 6) + (i << 4) + (lane & 15)) * 64 + kfs]);
        bfr[i] = *(const bf16x8*)(&lB[((wc << 6) + (i << 4) + (lane & 15)) * 64 + kfs]);
      }
#pragma unroll
      for (int i = 0; i < 4; i++)
#pragma unroll
        for (int j = 0; j < 4; j++)
          acc[i][j] = __builtin_amdgcn_mfma_f32_16x16x32_bf16(af[i], bfr[j], acc[i][j], 0, 0, 0);
    }
    __syncthreads();                    // reads done; safe to overwrite next tile
  }
  // epilogue: C/D layout col=lane&15, row=(lane>>4)*4+q (m89/m91-verified)
#pragma unroll
  for (int i = 0; i < 4; i++) {
    int rbase = n0 + wr * 64 + i * 16 + ((lane >> 4) << 2);
#pragma unroll
    for (int j = 0; j < 4; j++) {
      int col = m0 + wc * 64 + j * 16 + (lane & 15);
      float bv = BIAS ? bias[col] : 0.0f;
#pragma unroll
      for (int q = 0; q < 4; q++) {
        float vv = acc[i][j][q] + bv;
        if (ACT == 1) vv = 0.5f * vv * (1.0f + erff(vv * 0.70710678118f));
        if (ACT == 2 && col < DMODEL) vv *= QSCALE;
        st_out(C, (long)(rbase + q) * ldc + col, vv);
      }
    }
  }
}

// ---------------- fused flash attention (exp2 domain, l via ones-MFMA) ----------------
#define QBLK 64
#define KBLK 128
__global__ __launch_bounds__(256) void flash_attn(
    const ushort* __restrict__ qkv, const ushort* __restrict__ vt,
    ushort* __restrict__ attn) {
  __shared__ __align__(16) ushort lK[2][KBLK * 64];
  __shared__ __align__(16) ushort lV[2][64 * KBLK];
  __shared__ __align__(16) ushort lP[4 * 16 * KBLK];

  int qt = blockIdx.x, bh = blockIdx.z;
  int b = bh >> 4, hh = bh & 15;
  int tid = threadIdx.x, lane = tid & 63, wid = tid >> 6;
  int lo = lane & 15, hi = lane >> 4;
  int lrow = lane >> 3;
  int swz8 = ((lane & 7) ^ lrow) << 3;

  const ushort* Qg = qkv + (long)(b * 1024 + qt * QBLK) * 3072 + hh * 64;
  const ushort* Kg = qkv + (long)(b * 1024) * 3072 + 1024 + hh * 64;
  const ushort* Vg = vt + (long)bh * 64 * 1024;
  ushort* lPw = lP + wid * (16 * KBLK);

  bf16x8 kOnes;
#pragma unroll
  for (int i = 0; i < 8; ++i) kOnes[i] = (short)0x3F80;   // bf16 1.0

  auto STAGE = [&](int t, int buf) {
#pragma unroll
    for (int c = 0; c < 4; ++c) {
      int ch = (wid << 2) | c;
      int rb = (ch << 3) + lrow;
      gld_lds16(Kg + (long)(t * KBLK + rb) * 3072 + swz8, &lK[buf][ch << 9]);
    }
#pragma unroll
    for (int c = 0; c < 4; ++c) {
      int ch = (wid << 2) | c;
      int hd = (ch << 2) + hi;
      gld_lds16(Vg + (long)hd * 1024 + t * KBLK + ((lo ^ (hd & 7)) << 3), &lV[buf][ch << 9]);
    }
  };

#pragma unroll
  for (int c = 0; c < 2; ++c) {
    int ch = wid * 2 + c;
    int rb = ch * 8 + lrow;
    gld_lds16(Qg + (long)rb * 3072 + swz8, &lP[ch << 9]);
  }
  STAGE(0, 0);
  asm volatile("s_waitcnt vmcnt(8)" ::: "memory");
  __builtin_amdgcn_sched_barrier(0);
  bf16x8 a_q[2];
#pragma unroll
  for (int kk = 0; kk < 2; ++kk)
    a_q[kk] = *(const bf16x8*)&lP[(wid * 16 + lo) * 64 + (((kk * 4 + hi) ^ (lo & 7)) << 3)];
  asm volatile("s_waitcnt lgkmcnt(0)" ::: "memory");
  __builtin_amdgcn_sched_barrier(0);
  __builtin_amdgcn_s_barrier();

  float m_run[4];
#pragma unroll
  for (int q = 0; q < 4; ++q) m_run[q] = -1e30f;
  f32x4 acc_o[4];
#pragma unroll
  for (int j = 0; j < 4; ++j) acc_o[j] = (f32x4){0.f, 0.f, 0.f, 0.f};
  f32x4 acc_l = (f32x4){0.f, 0.f, 0.f, 0.f};   // row-sums via ones-MFMA

  for (int t = 0; t < 8; ++t) {
    int cur = t & 1;
    if (t + 1 < 8) {
      STAGE(t + 1, cur ^ 1);
      asm volatile("s_waitcnt vmcnt(8)" ::: "memory");
    } else {
      asm volatile("s_waitcnt vmcnt(0)" ::: "memory");
    }
    __builtin_amdgcn_s_barrier();
    __builtin_amdgcn_sched_barrier(0);

    // ---- QK^T (logits already in exp2 domain via Q pre-scale) ----
    f32x4 s[8];
#pragma unroll
    for (int j = 0; j < 8; ++j) s[j] = (f32x4){0.f, 0.f, 0.f, 0.f};
    __builtin_amdgcn_s_setprio(1);
#pragma unroll
    for (int kk = 0; kk < 2; ++kk) {
      int slot = ((kk * 4 + hi) ^ (lo & 7)) << 3;
#pragma unroll
      for (int j = 0; j < 8; ++j) {
        bf16x8 bk = *(const bf16x8*)&lK[cur][(j * 16 + lo) * 64 + slot];
        s[j] = __builtin_amdgcn_mfma_f32_16x16x32_bf16(a_q[kk], bk, s[j], 0, 0, 0);
      }
    }
    __builtin_amdgcn_s_setprio(0);

    // ---- online max (16-lane shuffles, register stats) ----
    float alpha[4];
#pragma unroll
    for (int q = 0; q < 4; ++q) {
      float m = fmaxf(fmaxf(fmaxf(s[0][q], s[1][q]), fmaxf(s[2][q], s[3][q])),
                      fmaxf(fmaxf(s[4][q], s[5][q]), fmaxf(s[6][q], s[7][q])));
#pragma unroll
      for (int off = 1; off < 16; off <<= 1) m = fmaxf(m, __shfl_xor(m, off));
      float mnew = fmaxf(m_run[q], m);
      alpha[q] = __builtin_amdgcn_exp2f(m_run[q] - mnew);
      m_run[q] = mnew;
    }
    // ---- P = exp2(s-m) -> LDS (bf16 via HW cvt, swizzled) ----
#pragma unroll
    for (int j = 0; j < 8; ++j)
#pragma unroll
      for (int q = 0; q < 4; ++q) {
        float e = __builtin_amdgcn_exp2f(s[j][q] - m_run[q]);
        int row = hi * 4 + q;
        int col = j * 16 + lo;
        lPw[row * KBLK + (col ^ ((row & 7) << 3))] = f2bf_hw(e);
      }

    // ---- PV + row-sum; rescale by alpha ----
#pragma unroll
    for (int q = 0; q < 4; ++q) acc_l[q] *= alpha[q];
#pragma unroll
    for (int j = 0; j < 4; ++j)
#pragma unroll
      for (int q = 0; q < 4; ++q) acc_o[j][q] *= alpha[q];
    __builtin_amdgcn_s_setprio(1);
#pragma unroll
    for (int ks = 0; ks < 4; ++ks) {
      int slot = ((ks * 4 + hi) ^ (lo & 7)) << 3;
      bf16x8 ap = *(const bf16x8*)&lPw[lo * KBLK + slot];
      acc_l = __builtin_amdgcn_mfma_f32_16x16x32_bf16(ap, kOnes, acc_l, 0, 0, 0);
#pragma unroll
      for (int j = 0; j < 4; ++j) {
        bf16x8 bv = *(const bf16x8*)&lV[cur][(j * 16 + lo) * KBLK + slot];
        acc_o[j] = __builtin_amdgcn_mfma_f32_16x16x32_bf16(ap, bv, acc_o[j], 0, 0, 0);
      }
    }
    __builtin_amdgcn_s_setprio(0);
    asm volatile("s_waitcnt lgkmcnt(0)" ::: "memory");
    __builtin_amdgcn_s_barrier();
    __builtin_amdgcn_sched_barrier(0);
  }

#pragma unroll
  for (int q = 0; q < 4; ++q) {
    float linv = 1.0f / acc_l[q];
    int qrow = qt * QBLK + wid * 16 + hi * 4 + q;
#pragma unroll
    for (int j = 0; j < 4; ++j)
      attn[(long)(b * 1024 + qrow) * 1024 + hh * 64 + j * 16 + lo] = f2bf(acc_o[j][q] * linv);
  }
}

// ---------------- host orchestration ----------------
extern "C" void kernel_launch(void* const* d_in, const int* in_sizes, int n_in,
                              void* d_out, int out_size, void* d_ws, size_t ws_size,
                              hipStream_t stream) {
  const float* x    = (const float*)d_in[0];
  const float* wq   = (const float*)d_in[1];
  const float* bq   = (const float*)d_in[2];
  const float* wk   = (const float*)d_in[3];
  const float* bk   = (const float*)d_in[4];
  const float* wv   = (const float*)d_in[5];
  const float* bv   = (const float*)d_in[6];
  const float* wo   = (const float*)d_in[7];
  const float* bo   = (const float*)d_in[8];
  const float* w1   = (const float*)d_in[9];
  const float* b1   = (const float*)d_in[10];
  const float* w2   = (const float*)d_in[11];
  const float* b2   = (const float*)d_in[12];
  const float* ln1g = (const float*)d_in[13];
  const float* ln1b = (const float*)d_in[14];
  const float* ln2g = (const float*)d_in[15];
  const float* ln2b = (const float*)d_in[16];
  float* out = (float*)d_out;

  char* ws = (char*)d_ws;
  size_t off = 0;
  auto alloc = [&](size_t bytes) { void* p = ws + off; off += (bytes + 255) & ~(size_t)255; return p; };
  ushort* h     = (ushort*)alloc((size_t)NTOK * DMODEL * 2);        // 8MB
  ushort* wqkvT = (ushort*)alloc((size_t)3 * DMODEL * DMODEL * 2);  // 6MB
  ushort* woT   = (ushort*)alloc((size_t)DMODEL * DMODEL * 2);      // 2MB
  float*  bqkv  = (float*)alloc((size_t)3 * DMODEL * 4);            // 12KB
  ushort* qkv   = (ushort*)alloc((size_t)NTOK * 3 * DMODEL * 2);    // 24MB
  ushort* vt    = (ushort*)alloc((size_t)64 * HDIM * S_LEN * 2);    // 8MB [bh][hd][s]
  ushort* attn  = (ushort*)alloc((size_t)NTOK * DMODEL * 2);        // 8MB
  ushort* w1T   = (ushort*)alloc((size_t)DMODEL * FFDIM * 2);       // 8MB [FF][D]
  ushort* w2T   = (ushort*)alloc((size_t)FFDIM * DMODEL * 2);       // 8MB [D][FF]
  ushort* gact  = (ushort*)alloc((size_t)NTOK * FFDIM * 2);         // 32MB
  // dead-region overlays (qkv 24MB + vt 8MB = 32MB contiguous, dead after flash):
  ushort* woPart  = qkv;   // 4 x 8MB partials for wo
  ushort* ffnPart = qkv;   // 4 x 8MB partials for FFN2 (woPart dead after reduce_ln)

  dim3 tb32(32, 8);
  hipLaunchKernelGGL((transpose_cvt<float>), dim3(DMODEL/32, DMODEL/32, 1), tb32, 0, stream,
                     wq, wqkvT, DMODEL, DMODEL, 0, 0, 0);
  hipLaunchKernelGGL((transpose_cvt<float>), dim3(DMODEL/32, DMODEL/32, 1), tb32, 0, stream,
                     wk, wqkvT + (size_t)DMODEL * DMODEL, DMODEL, DMODEL, 0, 0, 0);
  hipLaunchKernelGGL((transpose_cvt<float>), dim3(DMODEL/32, DMODEL/32, 1), tb32, 0, stream,
                     wv, wqkvT + (size_t)2 * DMODEL * DMODEL, DMODEL, DMODEL, 0, 0, 0);
  hipLaunchKernelGGL((transpose_cvt<float>), dim3(DMODEL/32, DMODEL/32, 1), tb32, 0, stream,
                     wo, woT, DMODEL, DMODEL, 0, 0, 0);
  hipLaunchKernelGGL(concat3, dim3(12), dim3(256), 0, stream, bq, bk, bv, bqkv);

  // LN1
  hipLaunchKernelGGL(ln_kernel, dim3(NTOK), dim3(256), 0, stream, x, ln1g, ln1b, h);

  // merged QKV GEMM (m97 structure, 3 blocks/CU); ACT=2 pre-scales Q cols by QSCALE
  hipLaunchKernelGGL((gemm_bt<2, true, ushort>), dim3(24, 32, 1), dim3(256), 0, stream,
                     h, wqkvT, qkv, bqkv,
                     3 * DMODEL, DMODEL, DMODEL, DMODEL, 3 * DMODEL, 0L, 0L, 0L);

  // V transpose per (b,h): qkv[:, 2048 + h*64 ..] -> vt [bh][hd][s]
  hipLaunchKernelGGL((transpose_cvt<ushort>), dim3(HDIM/32, S_LEN/32, 64), tb32, 0, stream,
                     qkv + 2 * DMODEL, vt, 3 * DMODEL, S_LEN,
                     (long)S_LEN * 3 * DMODEL, 64L, (long)HDIM * S_LEN);

  // fused flash attention: 16 q-tiles x 64 (b,h)
  hipLaunchKernelGGL(flash_attn, dim3(16, 1, 64), dim3(256), 0, stream, qkv, vt, attn);

  // wo GEMM: split-K=4 bf16 partials (grid 1024 = 4/CU), then fused reduce+LN2:
  // out = x + bo + sum(p) ; h = LN2(out)
  hipLaunchKernelGGL((gemm_bt<0, false, ushort>), dim3(8, 32, 4), dim3(256), 0, stream,
                     attn, woT, woPart, (const float*)nullptr,
                     DMODEL, 256, DMODEL, DMODEL, DMODEL,
                     256L, 256L, (long)NTOK * DMODEL);
  hipLaunchKernelGGL((reduce_ln<4>), dim3(4096), dim3(256), 0, stream,
                     woPart, x, bo, out, ln2g, ln2b, h);
  // FFN weight transposes
  hipLaunchKernelGGL((transpose_cvt<float>), dim3(FFDIM/32, DMODEL/32, 1), tb32, 0, stream,
                     w1, w1T, FFDIM, DMODEL, 0, 0, 0);
  hipLaunchKernelGGL((transpose_cvt<float>), dim3(DMODEL/32, FFDIM/32, 1), tb32, 0, stream,
                     w2, w2T, DMODEL, FFDIM, 0, 0, 0);
  // FFN1: gelu(h @ w1 + b1) -> gact   (m97 structure, 4 blocks/CU)
  hipLaunchKernelGGL((gemm_bt<1, true, ushort>), dim3(32, 32, 1), dim3(256), 0, stream,
                     h, w1T, gact, b1,
                     FFDIM, DMODEL, DMODEL, DMODEL, FFDIM, 0L, 0L, 0L);
  // FFN2: split-K=4 bf16 partials (grid 1024 = 4/CU), then reduce: out += b2 + sum(p)
  hipLaunchKernelGGL((gemm_bt<0, false, ushort>), dim3(8, 32, 4), dim3(256), 0, stream,
                     gact, w2T, ffnPart, (const float*)nullptr,
                     DMODEL, 1024, FFDIM, FFDIM, DMODEL,
                     1024L, 1024L, (long)NTOK * DMODEL);
  hipLaunchKernelGGL((reduce_add<4>), dim3(4096), dim3(256), 0, stream,
                     ffnPart, b2, out);
  (void)in_sizes; (void)n_in; (void)out_size; (void)ws_size;
}

// Round 13
// 243.442 us; speedup vs baseline: 1.1794x; 1.1794x over previous
//
#include <hip/hip_runtime.h>
#include <hip/hip_bf16.h>
#include <cstdint>

// ---- problem constants ----
#define S_LEN  1024
#define DMODEL 1024
#define NTOK   4096   // B*S = 4*1024
#define NHEAD  16
#define HDIM   64
#define FFDIM  4096
#define NBATCH 4
#define QSCALE 0.1803368801f   // 0.125 * log2(e): folds attn scale + exp->exp2 into Q

using bf16x8 = __attribute__((ext_vector_type(8))) short;
using f32x4  = __attribute__((ext_vector_type(4))) float;

__device__ __forceinline__ ushort f2bf(float f) {
  union { float f; uint32_t u; } a; a.f = f;
  uint32_t u = a.u;
  u += 0x7FFFu + ((u >> 16) & 1u);   // RNE
  return (ushort)(u >> 16);
}
// HW pack-convert, 1 VALU op (RNE on gfx950)
__device__ __forceinline__ ushort f2bf_hw(float f) {
  uint32_t r;
  asm("v_cvt_pk_bf16_f32 %0, %1, %1" : "=v"(r) : "v"(f));
  return (ushort)r;
}
__device__ __forceinline__ float bf2f(ushort u) {
  union { uint32_t u; float f; } c; c.u = ((uint32_t)u) << 16; return c.f;
}
__device__ __forceinline__ void st_out(float* C, long i, float v) { C[i] = v; }
__device__ __forceinline__ void st_out(ushort* C, long i, float v) { C[i] = f2bf(v); }

// async global->LDS, 16B per lane; LDS dest = wave-uniform base + lane*16 (linear!)
__device__ __forceinline__ void gld_lds16(const void* g, void* l) {
  __builtin_amdgcn_global_load_lds((const __attribute__((address_space(1))) void*)g,
                                   (__attribute__((address_space(3))) void*)l, 16, 0, 0);
}

// ---------------- LayerNorm (row of 1024 f32) -> bf16 ----------------
__global__ __launch_bounds__(256) void ln_kernel(const float* __restrict__ x,
    const float* __restrict__ g, const float* __restrict__ b,
    ushort* __restrict__ out) {
  int row = blockIdx.x;
  int tid = threadIdx.x;
  const float4* xr = (const float4*)(x + (long)row * DMODEL);
  float4 v = xr[tid];
  float s  = v.x + v.y + v.z + v.w;
  float s2 = v.x*v.x + v.y*v.y + v.z*v.z + v.w*v.w;
  for (int off = 32; off; off >>= 1) { s += __shfl_down(s, off); s2 += __shfl_down(s2, off); }
  __shared__ float red[8];
  int wid = tid >> 6, lane = tid & 63;
  if (lane == 0) { red[wid] = s; red[wid + 4] = s2; }
  __syncthreads();
  if (tid == 0) {
    red[0] = red[0] + red[1] + red[2] + red[3];
    red[4] = red[4] + red[5] + red[6] + red[7];
  }
  __syncthreads();
  float mu  = red[0] * (1.0f / DMODEL);
  float var = red[4] * (1.0f / DMODEL) - mu * mu;
  float rs  = rsqrtf(var + 1e-5f);
  float4 gg = ((const float4*)g)[tid];
  float4 bb = ((const float4*)b)[tid];
  ushort4 o;
  o.x = f2bf((v.x - mu) * rs * gg.x + bb.x);
  o.y = f2bf((v.y - mu) * rs * gg.y + bb.y);
  o.z = f2bf((v.z - mu) * rs * gg.z + bb.z);
  o.w = f2bf((v.w - mu) * rs * gg.w + bb.w);
  ((ushort4*)(out + (long)row * DMODEL))[tid] = o;
}

// ---------------- bias concat: [bq|bk|bv] -> 3072 floats ----------------
__global__ __launch_bounds__(256) void concat3(const float* __restrict__ a,
    const float* __restrict__ b, const float* __restrict__ c, float* __restrict__ o) {
  int i = blockIdx.x * 256 + threadIdx.x;
  o[i] = (i < 1024) ? a[i] : ((i < 2048) ? b[i - 1024] : c[i - 2048]);
}

// ---------------- partial reduce: out = out + bias + sum(parts) ----------------
template <int NP>
__global__ __launch_bounds__(256) void reduce_add(
    const ushort* __restrict__ parts, const float* __restrict__ bias,
    float* __restrict__ out) {
  long i = (long)blockIdx.x * 256 + threadIdx.x;   // float4 index
  const long PSTRIDE = (long)NTOK * DMODEL / 4;    // in ushort4 units
  float4 acc = ((const float4*)out)[i];
  float4 b = ((const float4*)bias)[i & 255];
  acc.x += b.x; acc.y += b.y; acc.z += b.z; acc.w += b.w;
#pragma unroll
  for (int z = 0; z < NP; ++z) {
    ushort4 u = ((const ushort4*)parts)[z * PSTRIDE + i];
    acc.x += bf2f(u.x); acc.y += bf2f(u.y); acc.z += bf2f(u.z); acc.w += bf2f(u.w);
  }
  ((float4*)out)[i] = acc;
}

// ---- fused: out = x + bias + sum(parts); hout = LN(out)*g+b (bf16). 1 block/row. ----
template <int NP>
__global__ __launch_bounds__(256) void reduce_ln(
    const ushort* __restrict__ parts, const float* __restrict__ xres,
    const float* __restrict__ bias, float* __restrict__ out,
    const float* __restrict__ g, const float* __restrict__ bln,
    ushort* __restrict__ hout) {
  int row = blockIdx.x, tid = threadIdx.x;
  long i = (long)row * 256 + tid;
  const long PSTRIDE = (long)NTOK * DMODEL / 4;
  float4 v = ((const float4*)xres)[i];
  float4 b = ((const float4*)bias)[tid];
  v.x += b.x; v.y += b.y; v.z += b.z; v.w += b.w;
#pragma unroll
  for (int z = 0; z < NP; ++z) {
    ushort4 u = ((const ushort4*)parts)[z * PSTRIDE + i];
    v.x += bf2f(u.x); v.y += bf2f(u.y); v.z += bf2f(u.z); v.w += bf2f(u.w);
  }
  ((float4*)out)[i] = v;
  // LN over the row
  float s  = v.x + v.y + v.z + v.w;
  float s2 = v.x*v.x + v.y*v.y + v.z*v.z + v.w*v.w;
  for (int off = 32; off; off >>= 1) { s += __shfl_down(s, off); s2 += __shfl_down(s2, off); }
  __shared__ float red[8];
  int wid = tid >> 6, lane = tid & 63;
  if (lane == 0) { red[wid] = s; red[wid + 4] = s2; }
  __syncthreads();
  if (tid == 0) {
    red[0] = red[0] + red[1] + red[2] + red[3];
    red[4] = red[4] + red[5] + red[6] + red[7];
  }
  __syncthreads();
  float mu  = red[0] * (1.0f / DMODEL);
  float var = red[4] * (1.0f / DMODEL) - mu * mu;
  float rs  = rsqrtf(var + 1e-5f);
  float4 gg = ((const float4*)g)[tid];
  float4 bb = ((const float4*)bln)[tid];
  ushort4 o;
  o.x = f2bf((v.x - mu) * rs * gg.x + bb.x);
  o.y = f2bf((v.y - mu) * rs * gg.y + bb.y);
  o.z = f2bf((v.z - mu) * rs * gg.z + bb.z);
  o.w = f2bf((v.w - mu) * rs * gg.w + bb.w);
  ((ushort4*)hout)[i] = o;
}

// ---------------- transpose + convert to bf16 (generic, used for V) ----------------
template <typename TIN>
__global__ __launch_bounds__(256) void transpose_cvt(const TIN* __restrict__ in,
    ushort* __restrict__ out, int ldin, int ldout,
    long inZhi, long inZlo, long outZ) {
  int z = blockIdx.z;
  in  += (long)(z >> 4) * inZhi + (long)(z & 15) * inZlo;
  out += (long)z * outZ;
  __shared__ float tile[32][33];
  int c0 = blockIdx.x * 32, r0 = blockIdx.y * 32;
  int tx = threadIdx.x, ty = threadIdx.y;
  for (int i = ty; i < 32; i += 8)
    tile[i][tx] = bf2f(in[(long)(r0 + i) * ldin + c0 + tx]);
  __syncthreads();
  for (int i = ty; i < 32; i += 8)
    out[(long)(c0 + i) * ldout + r0 + tx] = f2bf(tile[tx][i]);
}

// ---- merged transpose of the four DxD weights: outb + z*D*D <- W_z^T (bf16) ----
__global__ __launch_bounds__(256) void wt4(const float* __restrict__ wq,
    const float* __restrict__ wk, const float* __restrict__ wv,
    const float* __restrict__ wo, ushort* __restrict__ outb) {
  int z = blockIdx.z;
  const float* in = (z == 0) ? wq : (z == 1) ? wk : (z == 2) ? wv : wo;
  ushort* out = outb + (long)z * DMODEL * DMODEL;
  __shared__ float tile[32][33];
  int c0 = blockIdx.x * 32, r0 = blockIdx.y * 32;
  int tx = threadIdx.x, ty = threadIdx.y;
  for (int i = ty; i < 32; i += 8)
    tile[i][tx] = in[(long)(r0 + i) * DMODEL + c0 + tx];
  __syncthreads();
  for (int i = ty; i < 32; i += 8)
    out[(long)(c0 + i) * DMODEL + r0 + tx] = f2bf(tile[tx][i]);
}

// ---- merged transpose of w1 [D][FF]->w1T [FF][D] (z=0) and w2 [FF][D]->w2T [D][FF] (z=1) ----
__global__ __launch_bounds__(256) void w12t(const float* __restrict__ w1,
    const float* __restrict__ w2, ushort* __restrict__ w1T, ushort* __restrict__ w2T) {
  int z = blockIdx.z;
  __shared__ float tile[32][33];
  int tx = threadIdx.x, ty = threadIdx.y;
  if (z == 0) {
    int c0 = blockIdx.x * 32, r0 = blockIdx.y * 32;   // c over FF, r over D
    for (int i = ty; i < 32; i += 8)
      tile[i][tx] = w1[(long)(r0 + i) * FFDIM + c0 + tx];
    __syncthreads();
    for (int i = ty; i < 32; i += 8)
      w1T[(long)(c0 + i) * DMODEL + r0 + tx] = f2bf(tile[tx][i]);
  } else {
    int c0 = blockIdx.y * 32, r0 = blockIdx.x * 32;   // c over D, r over FF
    for (int i = ty; i < 32; i += 8)
      tile[i][tx] = w2[(long)(r0 + i) * DMODEL + c0 + tx];
    __syncthreads();
    for (int i = ty; i < 32; i += 8)
      w2T[(long)(c0 + i) * FFDIM + r0 + tx] = f2bf(tile[tx][i]);
  }
}

// ---------------- 128x128 bf16 MFMA GEMM, 2-deep pipelined (wo partials) ----------------
template <int ACT, bool BIAS, typename TOUT>
__global__ __launch_bounds__(256) void gemm_bt(
    const ushort* __restrict__ A, const ushort* __restrict__ BT, TOUT* __restrict__ C,
    const float* __restrict__ bias,
    int M, int K, int lda, int ldb, int ldc,
    long aZlo, long bZlo, long cZlo) {
  __shared__ __align__(16) ushort lA[2][128 * 64];
  __shared__ __align__(16) ushort lB[2][128 * 64];
  int z = blockIdx.z;
  A  += (long)z * aZlo;
  BT += (long)z * bZlo;
  C  += (long)z * cZlo;
  int gx = gridDim.x;
  int nwg = gx * gridDim.y;
  int lin = blockIdx.x + gx * blockIdx.y;
  int wg = (lin & 7) * (nwg >> 3) + (lin >> 3);
  int n0 = (wg / gx) * 128, m0 = (wg % gx) * 128;
  int tid = threadIdx.x, lane = tid & 63, wid = tid >> 6;
  int wr = wid >> 1, wc = wid & 1;
  int lrow = lane >> 3;
  int swz = ((lane & 7) ^ lrow) << 3;
  f32x4 acc[4][4];
#pragma unroll
  for (int i = 0; i < 4; i++)
#pragma unroll
    for (int j = 0; j < 4; j++) acc[i][j] = (f32x4){0.f, 0.f, 0.f, 0.f};

  auto STAGE = [&](int kt, int buf) {
    const ushort* Ak = A + (kt << 6) + swz;
    const ushort* Bk = BT + (kt << 6) + swz;
#pragma unroll
    for (int c = 0; c < 4; ++c) {
      int ch = (wid << 2) | c;
      int rb = (ch << 3) + lrow;
      gld_lds16(Ak + (long)(n0 + rb) * lda, &lA[buf][ch << 9]);
      gld_lds16(Bk + (long)(m0 + rb) * ldb, &lB[buf][ch << 9]);
    }
  };

  int nK = K >> 6;
  STAGE(0, 0);
  for (int kt = 0; kt < nK; ++kt) {
    int cur = kt & 1;
    if (kt + 1 < nK) {
      STAGE(kt + 1, cur ^ 1);
      asm volatile("s_waitcnt vmcnt(8)" ::: "memory");
    } else {
      asm volatile("s_waitcnt vmcnt(0)" ::: "memory");
    }
    __builtin_amdgcn_s_barrier();
    __builtin_amdgcn_sched_barrier(0);
#pragma unroll
    for (int kk = 0; kk < 2; ++kk) {
      int g = (kk << 2) | (lane >> 4);
      int kfs = ((g ^ (lane & 7)) << 3);
      bf16x8 af[4], bfr[4];
#pragma unroll
      for (int i = 0; i < 4; i++) {
        af[i]  = *(const bf16x8*)(&lA[cur][((wr << 6) + (i << 4) + (lane & 15)) * 64 + kfs]);
        bfr[i] = *(const bf16x8*)(&lB[cur][((wc << 6) + (i << 4) + (lane & 15)) * 64 + kfs]);
      }
#pragma unroll
      for (int i = 0; i < 4; i++)
#pragma unroll
        for (int j = 0; j < 4; j++)
          acc[i][j] = __builtin_amdgcn_mfma_f32_16x16x32_bf16(af[i], bfr[j], acc[i][j], 0, 0, 0);
    }
    asm volatile("s_waitcnt lgkmcnt(0)" ::: "memory");
    __builtin_amdgcn_s_barrier();
    __builtin_amdgcn_sched_barrier(0);
  }
#pragma unroll
  for (int i = 0; i < 4; i++) {
    int rbase = n0 + wr * 64 + i * 16 + ((lane >> 4) << 2);
#pragma unroll
    for (int j = 0; j < 4; j++) {
      int col = m0 + wc * 64 + j * 16 + (lane & 15);
      float bv = BIAS ? bias[col] : 0.0f;
#pragma unroll
      for (int q = 0; q < 4; q++) {
        float vv = acc[i][j][q] + bv;
        if (ACT == 1) vv = 0.5f * vv * (1.0f + erff(vv * 0.70710678118f));
        st_out(C, (long)(rbase + q) * ldc + col, vv);
      }
    }
  }
}

// ---------------- 256x256 8-wave phased GEMM with counted-vmcnt pipeline ----------------
// (round-10 structure — best measured: ~60us/FFN GEMM)
// ACT: 0=none, 1=exact gelu, 2=scale cols<DMODEL by QSCALE (Q pre-scale for exp2 softmax).
template <int ACT, bool BIAS, typename TOUT>
__global__ __launch_bounds__(512, 2) void gemm256(
    const ushort* __restrict__ A, const ushort* __restrict__ BT, TOUT* __restrict__ C,
    const float* __restrict__ bias,
    int K, int lda, int ldb, int ldc, long aZlo, long bZlo, long cZlo) {
  __shared__ __align__(16) ushort lA[2][256 * 64];   // 64KB
  __shared__ __align__(16) ushort lB[2][256 * 64];   // 64KB
  int z = blockIdx.z;
  A  += (long)z * aZlo;
  BT += (long)z * bZlo;
  C  += (long)z * cZlo;
  int gx = gridDim.x;
  int nwg = gx * gridDim.y;
  int lin = blockIdx.x + gx * blockIdx.y;
  int wg = (lin & 7) * (nwg >> 3) + (lin >> 3);
  int n0 = (wg / gx) * 256, m0 = (wg % gx) * 256;
  int tid = threadIdx.x, lane = tid & 63, wid = tid >> 6;
  int wm = wid >> 2, wn = wid & 3;
  int lo = lane & 15, hi = lane >> 4;
  int l7 = lane & 7;
  int srow = tid >> 3;                       // 0..63
  int skg  = (tid & 7) ^ (srow & 7);         // pre-swizzled global k-grp
  const ushort* gA = A + (long)(n0 + srow) * lda + (skg << 3);
  const ushort* gB = BT + (long)(m0 + srow) * ldb + (skg << 3);

  f32x4 acc[8][4];
#pragma unroll
  for (int i = 0; i < 8; ++i)
#pragma unroll
    for (int j = 0; j < 4; ++j) acc[i][j] = (f32x4){0.f, 0.f, 0.f, 0.f};

  auto STG = [&](int kt, int buf, int c) {
    if (c < 4)
      gld_lds16(gA + (long)(c * 64) * lda + (kt << 6), &lA[buf][c * 4096 + wid * 512]);
    else
      gld_lds16(gB + (long)((c - 4) * 64) * ldb + (kt << 6), &lB[buf][(c - 4) * 4096 + wid * 512]);
  };

  int nK = K >> 6;
  STG(0, 0, 4); STG(0, 0, 5); STG(0, 0, 6); STG(0, 0, 7);
  STG(0, 0, 0); STG(0, 0, 1); STG(0, 0, 2); STG(0, 0, 3);
  STG(1, 1, 4); STG(1, 1, 5); STG(1, 1, 6); STG(1, 1, 7);
  asm volatile("s_waitcnt vmcnt(4)" ::: "memory");
  __builtin_amdgcn_s_barrier();

  for (int t = 0; t < nK; ++t) {
    int cur = t & 1, nxt = cur ^ 1;
    ushort* plA = &lA[cur][0];
    ushort* plB = &lB[cur][0];
    bf16x8 bfr[4][2];
#pragma unroll
    for (int p = 0; p < 4; ++p) {
      if (p == 0) {
#pragma unroll
        for (int j = 0; j < 4; ++j)
#pragma unroll
          for (int kk = 0; kk < 2; ++kk)
            bfr[j][kk] = *(const bf16x8*)&plB[(wn * 64 + j * 16 + lo) * 64 +
                                             ((((kk << 2) | hi) ^ l7) << 3)];
      }
      bf16x8 afr[2][2];
#pragma unroll
      for (int ii = 0; ii < 2; ++ii)
#pragma unroll
        for (int kk = 0; kk < 2; ++kk)
          afr[ii][kk] = *(const bf16x8*)&plA[(wm * 128 + (p * 2 + ii) * 16 + lo) * 64 +
                                             ((((kk << 2) | hi) ^ l7) << 3)];
      if (p == 0 && t + 1 < nK) { STG(t + 1, nxt, 0); STG(t + 1, nxt, 1); }
      if (p == 1 && t + 1 < nK) { STG(t + 1, nxt, 2); STG(t + 1, nxt, 3); }
      if (p == 2 && t + 2 < nK) { STG(t + 2, cur, 4); STG(t + 2, cur, 5); }
      if (p == 3 && t + 2 < nK) { STG(t + 2, cur, 6); STG(t + 2, cur, 7); }
      __builtin_amdgcn_s_barrier();
      asm volatile("s_waitcnt lgkmcnt(0)" ::: "memory");
      __builtin_amdgcn_sched_barrier(0);
      __builtin_amdgcn_s_setprio(1);
#pragma unroll
      for (int ii = 0; ii < 2; ++ii)
#pragma unroll
        for (int j = 0; j < 4; ++j)
#pragma unroll
          for (int kk = 0; kk < 2; ++kk)
            acc[p * 2 + ii][j] = __builtin_amdgcn_mfma_f32_16x16x32_bf16(
                afr[ii][kk], bfr[j][kk], acc[p * 2 + ii][j], 0, 0, 0);
      __builtin_amdgcn_s_setprio(0);
      __builtin_amdgcn_sched_barrier(0);
      if (p == 3 && t + 1 < nK) {
        if (t + 2 < nK) asm volatile("s_waitcnt vmcnt(4)" ::: "memory");
        else            asm volatile("s_waitcnt vmcnt(0)" ::: "memory");
      }
      __builtin_amdgcn_s_barrier();
    }
  }

#pragma unroll
  for (int i = 0; i < 8; ++i) {
    int rbase = n0 + wm * 128 + i * 16 + hi * 4;
#pragma unroll
    for (int j = 0; j < 4; ++j) {
      int colg = m0 + wn * 64 + j * 16 + lo;
      float bv = BIAS ? bias[colg] : 0.0f;
#pragma unroll
      for (int q = 0; q < 4; ++q) {
        float vv = acc[i][j][q] + bv;
        if (ACT == 1) vv = 0.5f * vv * (1.0f + erff(vv * 0.70710678118f));
        if (ACT == 2 && colg < DMODEL) vv *= QSCALE;
        long idx = (long)(rbase + q) * ldc + colg;
        st_out(C, idx, vv);
      }
    }
  }
}

// ---------------- fused flash attention (exp2 domain, l via ones-MFMA) ----------------
#define QBLK 64
#define KBLK 128
__global__ __launch_bounds__(256) void flash_attn(
    const ushort* __restrict__ qkv, const ushort* __restrict__ vt,
    ushort* __restrict__ attn) {
  __shared__ __align__(16) ushort lK[2][KBLK * 64];
  __shared__ __align__(16) ushort lV[2][64 * KBLK];
  __shared__ __align__(16) ushort lP[4 * 16 * KBLK];

  int qt = blockIdx.x, bh = blockIdx.z;
  int b = bh >> 4, hh = bh & 15;
  int tid = threadIdx.x, lane = tid & 63, wid = tid >> 6;
  int lo = lane & 15, hi = lane >> 4;
  int lrow = lane >> 3;
  int swz8 = ((lane & 7) ^ lrow) << 3;

  const ushort* Qg = qkv + (long)(b * 1024 + qt * QBLK) * 3072 + hh * 64;
  const ushort* Kg = qkv + (long)(b * 1024) * 3072 + 1024 + hh * 64;
  const ushort* Vg = vt + (long)bh * 64 * 1024;
  ushort* lPw = lP + wid * (16 * KBLK);

  bf16x8 kOnes;
#pragma unroll
  for (int i = 0; i < 8; ++i) kOnes[i] = (short)0x3F80;   // bf16 1.0

  auto STAGE = [&](int t, int buf) {
#pragma unroll
    for (int c = 0; c < 4; ++c) {
      int ch = (wid << 2) | c;
      int rb = (ch << 3) + lrow;
      gld_lds16(Kg + (long)(t * KBLK + rb) * 3072 + swz8, &lK[buf][ch << 9]);
    }
#pragma unroll
    for (int c = 0; c < 4; ++c) {
      int ch = (wid << 2) | c;
      int hd = (ch << 2) + hi;
      gld_lds16(Vg + (long)hd * 1024 + t * KBLK + ((lo ^ (hd & 7)) << 3), &lV[buf][ch << 9]);
    }
  };

#pragma unroll
  for (int c = 0; c < 2; ++c) {
    int ch = wid * 2 + c;
    int rb = ch * 8 + lrow;
    gld_lds16(Qg + (long)rb * 3072 + swz8, &lP[ch << 9]);
  }
  STAGE(0, 0);
  asm volatile("s_waitcnt vmcnt(8)" ::: "memory");
  __builtin_amdgcn_sched_barrier(0);
  bf16x8 a_q[2];
#pragma unroll
  for (int kk = 0; kk < 2; ++kk)
    a_q[kk] = *(const bf16x8*)&lP[(wid * 16 + lo) * 64 + (((kk * 4 + hi) ^ (lo & 7)) << 3)];
  asm volatile("s_waitcnt lgkmcnt(0)" ::: "memory");
  __builtin_amdgcn_sched_barrier(0);
  __builtin_amdgcn_s_barrier();

  float m_run[4];
#pragma unroll
  for (int q = 0; q < 4; ++q) m_run[q] = -1e30f;
  f32x4 acc_o[4];
#pragma unroll
  for (int j = 0; j < 4; ++j) acc_o[j] = (f32x4){0.f, 0.f, 0.f, 0.f};
  f32x4 acc_l = (f32x4){0.f, 0.f, 0.f, 0.f};   // row-sums via ones-MFMA

  for (int t = 0; t < 8; ++t) {
    int cur = t & 1;
    if (t + 1 < 8) {
      STAGE(t + 1, cur ^ 1);
      asm volatile("s_waitcnt vmcnt(8)" ::: "memory");
    } else {
      asm volatile("s_waitcnt vmcnt(0)" ::: "memory");
    }
    __builtin_amdgcn_s_barrier();
    __builtin_amdgcn_sched_barrier(0);

    // ---- QK^T (logits already in exp2 domain via Q pre-scale) ----
    f32x4 s[8];
#pragma unroll
    for (int j = 0; j < 8; ++j) s[j] = (f32x4){0.f, 0.f, 0.f, 0.f};
    __builtin_amdgcn_s_setprio(1);
#pragma unroll
    for (int kk = 0; kk < 2; ++kk) {
      int slot = ((kk * 4 + hi) ^ (lo & 7)) << 3;
#pragma unroll
      for (int j = 0; j < 8; ++j) {
        bf16x8 bk = *(const bf16x8*)&lK[cur][(j * 16 + lo) * 64 + slot];
        s[j] = __builtin_amdgcn_mfma_f32_16x16x32_bf16(a_q[kk], bk, s[j], 0, 0, 0);
      }
    }
    __builtin_amdgcn_s_setprio(0);

    // ---- online max (16-lane shuffles, register stats) ----
    float alpha[4];
#pragma unroll
    for (int q = 0; q < 4; ++q) {
      float m = fmaxf(fmaxf(fmaxf(s[0][q], s[1][q]), fmaxf(s[2][q], s[3][q])),
                      fmaxf(fmaxf(s[4][q], s[5][q]), fmaxf(s[6][q], s[7][q])));
#pragma unroll
      for (int off = 1; off < 16; off <<= 1) m = fmaxf(m, __shfl_xor(m, off));
      float mnew = fmaxf(m_run[q], m);
      alpha[q] = __builtin_amdgcn_exp2f(m_run[q] - mnew);
      m_run[q] = mnew;
    }
    // ---- P = exp2(s-m) -> LDS (bf16 via HW cvt, swizzled) ----
#pragma unroll
    for (int j = 0; j < 8; ++j)
#pragma unroll
      for (int q = 0; q < 4; ++q) {
        float e = __builtin_amdgcn_exp2f(s[j][q] - m_run[q]);
        int row = hi * 4 + q;
        int col = j * 16 + lo;
        lPw[row * KBLK + (col ^ ((row & 7) << 3))] = f2bf_hw(e);
      }

    // ---- PV + row-sum; rescale by alpha ----
#pragma unroll
    for (int q = 0; q < 4; ++q) acc_l[q] *= alpha[q];
#pragma unroll
    for (int j = 0; j < 4; ++j)
#pragma unroll
      for (int q = 0; q < 4; ++q) acc_o[j][q] *= alpha[q];
    __builtin_amdgcn_s_setprio(1);
#pragma unroll
    for (int ks = 0; ks < 4; ++ks) {
      int slot = ((ks * 4 + hi) ^ (lo & 7)) << 3;
      bf16x8 ap = *(const bf16x8*)&lPw[lo * KBLK + slot];
      acc_l = __builtin_amdgcn_mfma_f32_16x16x32_bf16(ap, kOnes, acc_l, 0, 0, 0);
#pragma unroll
      for (int j = 0; j < 4; ++j) {
        bf16x8 bv = *(const bf16x8*)&lV[cur][(j * 16 + lo) * KBLK + slot];
        acc_o[j] = __builtin_amdgcn_mfma_f32_16x16x32_bf16(ap, bv, acc_o[j], 0, 0, 0);
      }
    }
    __builtin_amdgcn_s_setprio(0);
    asm volatile("s_waitcnt lgkmcnt(0)" ::: "memory");
    __builtin_amdgcn_s_barrier();
    __builtin_amdgcn_sched_barrier(0);
  }

#pragma unroll
  for (int q = 0; q < 4; ++q) {
    float linv = 1.0f / acc_l[q];
    int qrow = qt * QBLK + wid * 16 + hi * 4 + q;
#pragma unroll
    for (int j = 0; j < 4; ++j)
      attn[(long)(b * 1024 + qrow) * 1024 + hh * 64 + j * 16 + lo] = f2bf(acc_o[j][q] * linv);
  }
}

// ---------------- host orchestration ----------------
extern "C" void kernel_launch(void* const* d_in, const int* in_sizes, int n_in,
                              void* d_out, int out_size, void* d_ws, size_t ws_size,
                              hipStream_t stream) {
  const float* x    = (const float*)d_in[0];
  const float* wq   = (const float*)d_in[1];
  const float* bq   = (const float*)d_in[2];
  const float* wk   = (const float*)d_in[3];
  const float* bk   = (const float*)d_in[4];
  const float* wv   = (const float*)d_in[5];
  const float* bv   = (const float*)d_in[6];
  const float* wo   = (const float*)d_in[7];
  const float* bo   = (const float*)d_in[8];
  const float* w1   = (const float*)d_in[9];
  const float* b1   = (const float*)d_in[10];
  const float* w2   = (const float*)d_in[11];
  const float* b2   = (const float*)d_in[12];
  const float* ln1g = (const float*)d_in[13];
  const float* ln1b = (const float*)d_in[14];
  const float* ln2g = (const float*)d_in[15];
  const float* ln2b = (const float*)d_in[16];
  float* out = (float*)d_out;

  char* ws = (char*)d_ws;
  size_t off = 0;
  auto alloc = [&](size_t bytes) { void* p = ws + off; off += (bytes + 255) & ~(size_t)255; return p; };
  ushort* h     = (ushort*)alloc((size_t)NTOK * DMODEL * 2);        // 8MB
  ushort* wqkvT = (ushort*)alloc((size_t)3 * DMODEL * DMODEL * 2);  // 6MB
  ushort* woT   = (ushort*)alloc((size_t)DMODEL * DMODEL * 2);      // 2MB (== wqkvT+3*D*D)
  float*  bqkv  = (float*)alloc((size_t)3 * DMODEL * 4);            // 12KB
  ushort* qkv   = (ushort*)alloc((size_t)NTOK * 3 * DMODEL * 2);    // 24MB
  ushort* vt    = (ushort*)alloc((size_t)64 * HDIM * S_LEN * 2);    // 8MB [bh][hd][s]
  ushort* attn  = (ushort*)alloc((size_t)NTOK * DMODEL * 2);        // 8MB
  ushort* w1T   = (ushort*)alloc((size_t)DMODEL * FFDIM * 2);       // 8MB [FF][D]
  ushort* w2T   = (ushort*)alloc((size_t)FFDIM * DMODEL * 2);       // 8MB [D][FF]
  ushort* gact  = (ushort*)alloc((size_t)NTOK * FFDIM * 2);         // 32MB
  // dead-region overlays:
  ushort* woPart  = qkv;   // 2 x 8MB, live only after flash_attn (qkv dead)
  ushort* ffnPart = qkv;   // 4 x 8MB over qkv+vt, live during FFN2+reduce

  dim3 tb32(32, 8);
  // merged weight transposes: 4x DxD -> wqkvT(+woT contiguous); w1/w2 -> w1T/w2T
  hipLaunchKernelGGL(wt4, dim3(DMODEL/32, DMODEL/32, 4), tb32, 0, stream,
                     wq, wk, wv, wo, wqkvT);
  hipLaunchKernelGGL(w12t, dim3(FFDIM/32, DMODEL/32, 2), tb32, 0, stream,
                     w1, w2, w1T, w2T);
  hipLaunchKernelGGL(concat3, dim3(12), dim3(256), 0, stream, bq, bk, bv, bqkv);

  // LN1
  hipLaunchKernelGGL(ln_kernel, dim3(NTOK), dim3(256), 0, stream, x, ln1g, ln1b, h);

  // merged QKV GEMM (256² counted-vmcnt); ACT=2 pre-scales Q cols by QSCALE
  hipLaunchKernelGGL((gemm256<2, true, ushort>), dim3(12, 16, 1), dim3(512), 0, stream,
                     h, wqkvT, qkv, bqkv, DMODEL, DMODEL, DMODEL, 3 * DMODEL, 0L, 0L, 0L);

  // V transpose per (b,h): qkv[:, 2048 + h*64 ..] -> vt [bh][hd][s]
  hipLaunchKernelGGL((transpose_cvt<ushort>), dim3(HDIM/32, S_LEN/32, 64), tb32, 0, stream,
                     qkv + 2 * DMODEL, vt, 3 * DMODEL, S_LEN,
                     (long)S_LEN * 3 * DMODEL, 64L, (long)HDIM * S_LEN);

  // fused flash attention: 16 q-tiles x 64 (b,h)
  hipLaunchKernelGGL(flash_attn, dim3(16, 1, 64), dim3(256), 0, stream, qkv, vt, attn);

  // wo GEMM: split-K=2 bf16 partials, then fused reduce+LN2:
  // out = x + bo + p0 + p1 ; h = LN2(out)
  hipLaunchKernelGGL((gemm_bt<0, false, ushort>), dim3(8, 32, 2), dim3(256), 0, stream,
                     attn, woT, woPart, (const float*)nullptr,
                     DMODEL, 512, DMODEL, DMODEL, DMODEL,
                     512L, 512L, (long)NTOK * DMODEL);
  hipLaunchKernelGGL((reduce_ln<2>), dim3(4096), dim3(256), 0, stream,
                     woPart, x, bo, out, ln2g, ln2b, h);
  // FFN1: gelu(h @ w1 + b1) -> gact   (256² counted-vmcnt)
  hipLaunchKernelGGL((gemm256<1, true, ushort>), dim3(16, 16, 1), dim3(512), 0, stream,
                     h, w1T, gact, b1, DMODEL, DMODEL, DMODEL, FFDIM, 0L, 0L, 0L);
  // FFN2: split-K=4 bf16 partials, then reduce: out += b2 + sum(p)
  hipLaunchKernelGGL((gemm256<0, false, ushort>), dim3(4, 16, 4), dim3(512), 0, stream,
                     gact, w2T, ffnPart, (const float*)nullptr,
                     1024, FFDIM, FFDIM, DMODEL, 1024L, 1024L, (long)NTOK * DMODEL);
  hipLaunchKernelGGL((reduce_add<4>), dim3(4096), dim3(256), 0, stream,
                     ffnPart, b2, out);
  (void)in_sizes; (void)n_in; (void)out_size; (void)ws_size;
}